// Round 4
// baseline (274.046 us; speedup 1.0000x reference)
//
#include <hip/hip_runtime.h>

#define L 4096
#define HH 64
#define WW 64
#define DM 96
#define DI 192
#define DSTATE 16
#define DTR 6
#define NC 38   // DTR + 2*DSTATE
#define KD 4
#define CHUNK 16
#define NCHUNK 256  // L / CHUNK
#define NS 8        // states per thread (DSTATE/2)
#define TL 8        // l-tile for in_proj

__device__ __forceinline__ float silu_f(float v){ return v / (1.f + __expf(-v)); }
__device__ __forceinline__ float softplus_f(float v){ return fmaxf(v, 0.f) + log1pf(__expf(-fabsf(v))); }
// scan index l -> row-major spatial index for direction k
__device__ __forceinline__ int spat(int k, int l){
  int ll = (k & 2) ? (L - 1 - l) : l;
  return (k & 1) ? (((ll & 63) << 6) | (ll >> 6)) : ll;
}

// ---------------- Kernel 0: weight transposes (coalesced-access layouts) ----------------
__global__ void k_prep(const float* __restrict__ ipw, const float* __restrict__ pw,
                       const float* __restrict__ ow,
                       float* __restrict__ ipwT, float* __restrict__ pwT,
                       float* __restrict__ owT){
  int i = blockIdx.x * 256 + threadIdx.x;
  if (i < 384*DM){ int o = i / DM, c = i % DM; ipwT[c*384 + o] = ipw[i]; }
  int j = i - 384*DM;
  if (j >= 0 && j < KD*NC*DI){
    int k = j / (NC*DI); int r = j % (NC*DI); int c = r / DI, d = r % DI;
    pwT[(k*DI + d)*NC + c] = pw[j];
  }
  int m = i - 384*DM - KD*NC*DI;
  if (m >= 0 && m < DM*DI){ int o = m / DI, d = m % DI; owT[d*DM + o] = ow[m]; }
}

// ---------------- Kernel 1: in_proj -> x_ (L x 192), silu(z) (L x 192) ----------------
__global__ void k_inproj(const float* __restrict__ x, const float* __restrict__ wT,
                         float* __restrict__ xo, float* __restrict__ sz){
  int l0 = blockIdx.x * TL;          // grid = L/TL = 512
  int t  = threadIdx.x;              // 384 threads: one output channel each
  __shared__ float xl[TL][DM];
  for (int j = t; j < TL*DM; j += 384) xl[j / DM][j % DM] = x[l0*DM + j];
  __syncthreads();
  float acc[TL];
  #pragma unroll
  for (int i = 0; i < TL; i++) acc[i] = 0.f;
  #pragma unroll 4
  for (int c = 0; c < DM; c++){
    float wv = wT[c*384 + t];        // coalesced; L1/L2-resident
    #pragma unroll
    for (int i = 0; i < TL; i++) acc[i] += xl[i][c] * wv;  // LDS broadcast
  }
  if (t < DI){
    #pragma unroll
    for (int i = 0; i < TL; i++) xo[(l0 + i)*DI + t] = acc[i];
  } else {
    int z = t - DI;
    #pragma unroll
    for (int i = 0; i < TL; i++) sz[(l0 + i)*DI + z] = silu_f(acc[i]);
  }
}

// ---------------- Kernel 2: depthwise 3x3 conv + bias + silu -> xc ----------------
__global__ void k_conv(const float* __restrict__ xi, const float* __restrict__ cw,
                       const float* __restrict__ cb, float* __restrict__ xc){
  int idx = blockIdx.x * blockDim.x + threadIdx.x;
  if (idx >= L*DI) return;
  int d = idx % DI, l = idx / DI;
  int h = l >> 6, w = l & 63;
  float acc = cb[d];
  #pragma unroll
  for (int dy = 0; dy < 3; dy++){
    int hh = h + dy - 1;
    if (hh < 0 || hh >= HH) continue;
    #pragma unroll
    for (int dx = 0; dx < 3; dx++){
      int ww = w + dx - 1;
      if (ww < 0 || ww >= WW) continue;
      acc += xi[(hh*WW + ww)*DI + d] * cw[(dy*3 + dx)*DI + d];
    }
  }
  xc[idx] = silu_f(acc);
}

// ---------------- Kernel 3: x_dbl[k][l][38] = x_proj_w[k] @ xs[k,:,l] ----------------
__global__ void k_xdbl(const float* __restrict__ xc, const float* __restrict__ pwT,
                       float* __restrict__ xdbl){
  int k    = blockIdx.x >> 9;    // grid = 4*512
  int tile = blockIdx.x & 511;
  int l0   = tile * 8;
  int t    = threadIdx.x;        // 320 threads
  __shared__ float xt[8][DI + 1];   // +1 pad: kills bank conflict on xt[row][d]
  for (int j = t; j < 8*DI; j += 320){
    int row = j / DI, d = j - row*DI;
    xt[row][d] = xc[spat(k, l0 + row)*DI + d];
  }
  __syncthreads();
  int row = t / 40, c = t % 40;
  if (c < NC){
    const float* pr = pwT + k*DI*NC;
    float acc = 0.f;
    #pragma unroll 8
    for (int d = 0; d < DI; d++) acc += xt[row][d] * pr[d*NC + c];  // pr: lane-consecutive in c
    xdbl[(k*L + l0 + row)*NC + c] = acc;
  }
}

// ---------------- Kernel 4: scan pass 1 — per-chunk aggregates (P, G) ----------------
// block = 384 threads: pair (d, half); xc prestaged to LDS so the step loop is LDS/VALU-only
__global__ __launch_bounds__(384) void k_scan1(
    const float* __restrict__ xdbl, const float* __restrict__ xc,
    const float* __restrict__ dtw, const float* __restrict__ dtb,
    const float* __restrict__ alogs,
    float* __restrict__ Pb, float* __restrict__ Gb){
  int k  = blockIdx.x >> 8;   // grid = 4*256
  int ch = blockIdx.x & 255;
  int l0 = ch * CHUNK;
  int t  = threadIdx.x;
  int d  = t >> 1, half = t & 1;
  __shared__ float xd[CHUNK*NC];
  __shared__ float sxc[CHUNK][DI];
  for (int j = t; j < CHUNK*NC; j += 384) xd[j] = xdbl[(k*L + l0)*NC + j];
  for (int j = t; j < CHUNK*DI; j += 384){
    int i = j / DI, dd = j % DI;
    sxc[i][dd] = xc[spat(k, l0 + i)*DI + dd];   // coalesced 192-float rows
  }
  float wr[DTR];
  #pragma unroll
  for (int r = 0; r < DTR; r++) wr[r] = dtw[(k*DI + d)*DTR + r];
  float bb = dtb[k*DI + d];
  float A[NS];
  const float* ap = alogs + (k*DI + d)*DSTATE + half*NS;
  #pragma unroll
  for (int j = 0; j < NS; j++) A[j] = -__expf(ap[j]);
  float P[NS], G[NS];
  #pragma unroll
  for (int j = 0; j < NS; j++){ P[j] = 1.f; G[j] = 0.f; }
  __syncthreads();
  #pragma unroll
  for (int i = 0; i < CHUNK; i++){
    float xval = sxc[i][d];
    const float* row = xd + i*NC;
    float dv = bb;
    #pragma unroll
    for (int r = 0; r < DTR; r++) dv += wr[r] * row[r];
    dv = softplus_f(dv);
    float tv = dv * xval;
    const float* Brow = row + DTR + half*NS;
    #pragma unroll
    for (int j = 0; j < NS; j++){
      float dA = __expf(dv * A[j]);
      G[j] = dA * G[j] + tv * Brow[j];
      P[j] *= dA;
    }
  }
  float* Pp = Pb + ((size_t)(k*NCHUNK + ch)*DI*DSTATE) + t*NS;
  float* Gp = Gb + ((size_t)(k*NCHUNK + ch)*DI*DSTATE) + t*NS;
  #pragma unroll
  for (int j = 0; j < NS; j++){ Pp[j] = P[j]; Gp[j] = G[j]; }
}

// ---------------- Kernel 5: scan pass 2 — parallel (Hillis-Steele) prefix over chunks ----
__global__ void k_scan2(const float* __restrict__ Pb, const float* __restrict__ Gb,
                        float* __restrict__ Hin){
  int k = blockIdx.x / DI;
  int d = blockIdx.x % DI;
  int c = threadIdx.x;   // chunk id, 256 threads
  float P[DSTATE], G[DSTATE];
  const float* Pp = Pb + ((size_t)(k*NCHUNK + c)*DI + d)*DSTATE;
  const float* Gp = Gb + ((size_t)(k*NCHUNK + c)*DI + d)*DSTATE;
  #pragma unroll
  for (int n = 0; n < DSTATE; n++){ P[n] = Pp[n]; G[n] = Gp[n]; }
  __shared__ float sP[NCHUNK][DSTATE + 1];
  __shared__ float sG[NCHUNK][DSTATE + 1];
  for (int off = 1; off < NCHUNK; off <<= 1){
    #pragma unroll
    for (int n = 0; n < DSTATE; n++){ sP[c][n] = P[n]; sG[c][n] = G[n]; }
    __syncthreads();
    if (c >= off){
      #pragma unroll
      for (int n = 0; n < DSTATE; n++){
        float a1 = sP[c - off][n], b1 = sG[c - off][n];
        G[n] = P[n]*b1 + G[n];
        P[n] = P[n]*a1;
      }
    }
    __syncthreads();
  }
  #pragma unroll
  for (int n = 0; n < DSTATE; n++) sG[c][n] = G[n];
  __syncthreads();
  float* Hp = Hin + ((size_t)(k*NCHUNK + c)*DI + d)*DSTATE;
  #pragma unroll
  for (int n = 0; n < DSTATE; n++) Hp[n] = (c == 0) ? 0.f : sG[c - 1][n];
}

// -------- Kernel 6: scan pass 3 fused: all 4 k's + k-sum + LN + silu(z)*y + out-proj ----
// one block per chunk; 384 threads = (d, half); 4 independent recurrence chains per thread
__global__ __launch_bounds__(384) void k_scan3f(
    const float* __restrict__ xdbl, const float* __restrict__ xc,
    const float* __restrict__ dtw, const float* __restrict__ dtb,
    const float* __restrict__ alogs, const float* __restrict__ Dsv,
    const float* __restrict__ Hin, const float* __restrict__ sz,
    const float* __restrict__ lng, const float* __restrict__ lnb,
    const float* __restrict__ owT, float* __restrict__ out){
  int ch = blockIdx.x;          // 256 blocks
  int l0 = ch * CHUNK;
  int t  = threadIdx.x;
  int d  = t >> 1, half = t & 1;
  __shared__ float xd[KD][CHUNK*NC];      // 9.7 KB
  __shared__ float sxc[KD][CHUNK][DI];    // 49.2 KB
  __shared__ float ym[CHUNK][DI];         // 12.3 KB
  __shared__ float redS[CHUNK][26];
  __shared__ float redQ[CHUNK][26];
  __shared__ float muv[CHUNK], rsv[CHUNK];
  for (int j = t; j < KD*CHUNK*NC; j += 384){
    int k = j / (CHUNK*NC), r = j % (CHUNK*NC);
    xd[k][r] = xdbl[(k*L + l0)*NC + r];
  }
  for (int j = t; j < KD*CHUNK*DI; j += 384){
    int k = j / (CHUNK*DI), r = j % (CHUNK*DI);
    int i = r / DI, dd = r % DI;
    sxc[k][i][dd] = xc[spat(k, l0 + i)*DI + dd];
  }
  float wr[KD][DTR], bb[KD], A[KD][NS], h[KD][NS], Dvv[KD];
  #pragma unroll
  for (int k = 0; k < KD; k++){
    #pragma unroll
    for (int r = 0; r < DTR; r++) wr[k][r] = dtw[(k*DI + d)*DTR + r];
    bb[k] = dtb[k*DI + d];
    const float* ap = alogs + (k*DI + d)*DSTATE + half*NS;
    #pragma unroll
    for (int j = 0; j < NS; j++) A[k][j] = -__expf(ap[j]);
    const float* Hp = Hin + ((size_t)(k*NCHUNK + ch)*DI*DSTATE) + t*NS;
    #pragma unroll
    for (int j = 0; j < NS; j++) h[k][j] = Hp[j];
    Dvv[k] = Dsv[k*DI + d];
  }
  __syncthreads();
  #pragma unroll 4
  for (int i = 0; i < CHUNK; i++){
    float y = 0.f;
    #pragma unroll
    for (int k = 0; k < KD; k++){
      float xval = sxc[k][i][d];
      const float* row = &xd[k][i*NC];
      float dv = bb[k];
      #pragma unroll
      for (int r = 0; r < DTR; r++) dv += wr[k][r] * row[r];
      dv = softplus_f(dv);
      float tv = dv * xval;
      const float* Brow = row + DTR + half*NS;
      const float* Crow = row + DTR + DSTATE + half*NS;
      if (half == 0) y += Dvv[k] * xval;
      #pragma unroll
      for (int j = 0; j < NS; j++){
        float dA = __expf(dv * A[k][j]);
        h[k][j] = dA * h[k][j] + tv * Brow[j];
        y += h[k][j] * Crow[j];
      }
    }
    y += __shfl_xor(y, 1);        // combine state-halves (pair-adjacent lanes)
    if (half == 0) ym[i][d] = y;  // full 4-direction sum for (l0+i, d)
  }
  __syncthreads();
  // LayerNorm stats: 384 threads = 16 l's x 24 threads, each sums 8 d's (stride-24: conflict-free)
  {
    int i2 = t / 24, j2 = t % 24;
    float s = 0.f, s2 = 0.f;
    #pragma unroll
    for (int q = 0; q < 8; q++){ float v = ym[i2][j2 + 24*q]; s += v; s2 += v*v; }
    redS[i2][j2] = s; redQ[i2][j2] = s2;
  }
  __syncthreads();
  if (t < CHUNK){
    float S = 0.f, SQ = 0.f;
    #pragma unroll
    for (int q = 0; q < 24; q++){ S += redS[t][q]; SQ += redQ[t][q]; }
    float mu = S * (1.f/DI), var = SQ * (1.f/DI) - mu*mu;
    muv[t] = mu; rsv[t] = rsqrtf(var + 1e-5f);
  }
  __syncthreads();
  for (int j = t; j < CHUNK*DI; j += 384){
    int i = j / DI, dd = j % DI;
    float yn = (ym[i][dd] - muv[i]) * rsv[i] * lng[dd] + lnb[dd];
    ym[i][dd] = yn * sz[(size_t)(l0 + i)*DI + dd];
  }
  __syncthreads();
  for (int j = t; j < CHUNK*DM; j += 384){
    int i = j / DM, o = j % DM;
    float acc = 0.f;
    #pragma unroll 8
    for (int dd = 0; dd < DI; dd++) acc += ym[i][dd] * owT[dd*DM + o];  // lanes o-contig
    out[(l0 + i)*DM + o] = acc;
  }
}

extern "C" void kernel_launch(void* const* d_in, const int* in_sizes, int n_in,
                              void* d_out, int out_size, void* d_ws, size_t ws_size,
                              hipStream_t stream){
  const float* x   = (const float*)d_in[0];
  const float* ipw = (const float*)d_in[1];
  const float* cw  = (const float*)d_in[2];
  const float* cb  = (const float*)d_in[3];
  const float* pw  = (const float*)d_in[4];
  const float* dtw = (const float*)d_in[5];
  const float* dtb = (const float*)d_in[6];
  const float* alg = (const float*)d_in[7];
  const float* Dsv = (const float*)d_in[8];
  const float* lng = (const float*)d_in[9];
  const float* lnb = (const float*)d_in[10];
  const float* ow  = (const float*)d_in[11];
  float* out = (float*)d_out;

  float* ws    = (float*)d_ws;
  float* x_    = ws; ws += L*DI;
  float* sz    = ws; ws += L*DI;
  float* xc    = ws; ws += L*DI;
  float* xdbl  = ws; ws += KD*L*NC;
  float* Pb    = ws; ws += KD*NCHUNK*DI*DSTATE;
  float* Gb    = ws; ws += KD*NCHUNK*DI*DSTATE;
  float* Hin   = ws; ws += KD*NCHUNK*DI*DSTATE;
  float* ipwT  = ws; ws += 384*DM;
  float* pwT   = ws; ws += KD*NC*DI;
  float* owT   = ws; ws += DM*DI;

  k_prep<<<(384*DM + KD*NC*DI + DM*DI + 255)/256, 256, 0, stream>>>(ipw, pw, ow, ipwT, pwT, owT);
  k_inproj<<<L/TL, 384, 0, stream>>>(x, ipwT, x_, sz);
  k_conv<<<(L*DI + 255)/256, 256, 0, stream>>>(x_, cw, cb, xc);
  k_xdbl<<<KD*512, 320, 0, stream>>>(xc, pwT, xdbl);
  k_scan1<<<KD*NCHUNK, 384, 0, stream>>>(xdbl, xc, dtw, dtb, alg, Pb, Gb);
  k_scan2<<<KD*DI, NCHUNK, 0, stream>>>(Pb, Gb, Hin);
  k_scan3f<<<NCHUNK, 384, 0, stream>>>(xdbl, xc, dtw, dtb, alg, Dsv, Hin, sz, lng, lnb, owT, out);
}

// Round 5
// 230.648 us; speedup vs baseline: 1.1882x; 1.1882x over previous
//
#include <hip/hip_runtime.h>

#define L 4096
#define HH 64
#define WW 64
#define DM 96
#define DI 192
#define DSTATE 16
#define DTR 6
#define NC 38   // DTR + 2*DSTATE
#define KD 4
#define CHUNK 16
#define NCHUNK 256  // L / CHUNK
#define NS 8        // states per thread (DSTATE/2)
#define TL 8        // l-tile for in_proj
#define LOG2E 1.44269504f
#define LN2   0.69314718f

__device__ __forceinline__ float silu_f(float v){ return v / (1.f + __expf(-v)); }
__device__ __forceinline__ float softplus_f(float v){
  float a = fabsf(v);
  float e = exp2f(-a * LOG2E);            // v_exp_f32
  return fmaxf(v, 0.f) + LN2 * log2f(1.f + e);  // v_log_f32
}
// scan index l -> row-major spatial index for direction k
__device__ __forceinline__ int spat(int k, int l){
  int ll = (k & 2) ? (L - 1 - l) : l;
  return (k & 1) ? (((ll & 63) << 6) | (ll >> 6)) : ll;
}

// ---------------- Kernel 0: weight transposes (coalesced-access layouts) ----------------
__global__ void k_prep(const float* __restrict__ ipw, const float* __restrict__ pw,
                       const float* __restrict__ ow,
                       float* __restrict__ ipwT, float* __restrict__ pwT,
                       float* __restrict__ owT){
  int i = blockIdx.x * 256 + threadIdx.x;
  if (i < 384*DM){ int o = i / DM, c = i % DM; ipwT[c*384 + o] = ipw[i]; }
  int j = i - 384*DM;
  if (j >= 0 && j < KD*NC*DI){
    int k = j / (NC*DI); int r = j % (NC*DI); int c = r / DI, d = r % DI;
    pwT[(k*DI + d)*NC + c] = pw[j];
  }
  int m = i - 384*DM - KD*NC*DI;
  if (m >= 0 && m < DM*DI){ int o = m / DI, d = m % DI; owT[d*DM + o] = ow[m]; }
}

// ---------------- Kernel 1: in_proj -> x_ (L x 192), silu(z) (L x 192) ----------------
__global__ void k_inproj(const float* __restrict__ x, const float* __restrict__ wT,
                         float* __restrict__ xo, float* __restrict__ sz){
  int l0 = blockIdx.x * TL;          // grid = L/TL = 512
  int t  = threadIdx.x;              // 384 threads
  __shared__ float xl[TL][DM];
  for (int j = t; j < TL*DM; j += 384) xl[j / DM][j % DM] = x[l0*DM + j];
  __syncthreads();
  float acc[TL];
  #pragma unroll
  for (int i = 0; i < TL; i++) acc[i] = 0.f;
  #pragma unroll 4
  for (int c = 0; c < DM; c++){
    float wv = wT[c*384 + t];
    #pragma unroll
    for (int i = 0; i < TL; i++) acc[i] += xl[i][c] * wv;
  }
  if (t < DI){
    #pragma unroll
    for (int i = 0; i < TL; i++) xo[(l0 + i)*DI + t] = acc[i];
  } else {
    int z = t - DI;
    #pragma unroll
    for (int i = 0; i < TL; i++) sz[(l0 + i)*DI + z] = silu_f(acc[i]);
  }
}

// ---------------- Kernel 2: depthwise 3x3 conv + bias + silu -> xc ----------------
__global__ void k_conv(const float* __restrict__ xi, const float* __restrict__ cw,
                       const float* __restrict__ cb, float* __restrict__ xc){
  int idx = blockIdx.x * blockDim.x + threadIdx.x;
  if (idx >= L*DI) return;
  int d = idx % DI, l = idx / DI;
  int h = l >> 6, w = l & 63;
  float acc = cb[d];
  #pragma unroll
  for (int dy = 0; dy < 3; dy++){
    int hh = h + dy - 1;
    if (hh < 0 || hh >= HH) continue;
    #pragma unroll
    for (int dx = 0; dx < 3; dx++){
      int ww = w + dx - 1;
      if (ww < 0 || ww >= WW) continue;
      acc += xi[(hh*WW + ww)*DI + d] * cw[(dy*3 + dx)*DI + d];
    }
  }
  xc[idx] = silu_f(acc);
}

// ---------------- Kernel 3: x_dbl[k][l][38] = x_proj_w[k] @ xs[k,:,l] ----------------
__global__ void k_xdbl(const float* __restrict__ xc, const float* __restrict__ pwT,
                       float* __restrict__ xdbl){
  int k    = blockIdx.x >> 9;    // grid = 4*512
  int tile = blockIdx.x & 511;
  int l0   = tile * 8;
  int t    = threadIdx.x;        // 320 threads
  __shared__ float xt[8][DI + 1];
  for (int j = t; j < 8*DI; j += 320){
    int row = j / DI, d = j - row*DI;
    xt[row][d] = xc[spat(k, l0 + row)*DI + d];
  }
  __syncthreads();
  int row = t / 40, c = t % 40;
  if (c < NC){
    const float* pr = pwT + k*DI*NC;
    float acc = 0.f;
    #pragma unroll 8
    for (int d = 0; d < DI; d++) acc += xt[row][d] * pr[d*NC + c];
    xdbl[(k*L + l0 + row)*NC + c] = acc;
  }
}

// ---------------- Kernel 4: scan pass 1 — per-chunk aggregates (P, G) ----------------
// block = 384 threads: (d = t>>1, half = t&1). LDS laid out for b128 broadcast reads.
__global__ __launch_bounds__(384) void k_scan1(
    const float* __restrict__ xdbl, const float* __restrict__ xc,
    const float* __restrict__ dtw, const float* __restrict__ dtb,
    const float* __restrict__ alogs,
    float* __restrict__ Pb, float* __restrict__ Gb){
  int k  = blockIdx.x >> 8;   // grid = 4*256
  int ch = blockIdx.x & 255;
  int l0 = ch * CHUNK;
  int t  = threadIdx.x;
  int d  = t >> 1, half = t & 1;
  __shared__ float sdt[CHUNK][8];     // dt-rank coeffs (6 used)
  __shared__ float sB[CHUNK][16];     // 64B rows -> float4-aligned halves
  __shared__ float sC_unused[1];
  __shared__ float sxc[CHUNK][DI];
  (void)sC_unused;
  for (int j = t; j < CHUNK*NC; j += 384){
    int i = j / NC, c = j % NC;
    float v = xdbl[(size_t)(k*L + l0)*NC + j];   // contiguous, coalesced
    if (c < DTR) sdt[i][c] = v;
    else if (c < DTR + DSTATE) sB[i][c - DTR] = v;
    // C not needed in pass 1
  }
  for (int j = t; j < CHUNK*DI; j += 384){
    int i = j / DI, dd = j % DI;
    sxc[i][dd] = xc[spat(k, l0 + i)*DI + dd];
  }
  float wr[DTR];
  #pragma unroll
  for (int r = 0; r < DTR; r++) wr[r] = dtw[(k*DI + d)*DTR + r];
  float bb = dtb[k*DI + d];
  float A2[NS];
  const float* ap = alogs + (k*DI + d)*DSTATE + half*NS;
  #pragma unroll
  for (int j = 0; j < NS; j++) A2[j] = -__expf(ap[j]) * LOG2E;
  float P[NS], G[NS];
  #pragma unroll
  for (int j = 0; j < NS; j++){ P[j] = 1.f; G[j] = 0.f; }
  __syncthreads();
  #pragma unroll
  for (int i = 0; i < CHUNK; i++){
    float xval = sxc[i][d];                       // pair-broadcast, conflict-free
    float dv = bb;
    #pragma unroll
    for (int r = 0; r < DTR; r++) dv += wr[r] * sdt[i][r];   // wave-broadcast
    dv = softplus_f(dv);
    float tv = dv * xval;
    float4 b0 = *(const float4*)&sB[i][half*8];   // wave-broadcast b128
    float4 b1 = *(const float4*)&sB[i][half*8 + 4];
    float Bv[NS] = {b0.x,b0.y,b0.z,b0.w,b1.x,b1.y,b1.z,b1.w};
    #pragma unroll
    for (int j = 0; j < NS; j++){
      float dA = exp2f(dv * A2[j]);
      G[j] = dA * G[j] + tv * Bv[j];
      P[j] *= dA;
    }
  }
  size_t base = (size_t)(k*NCHUNK + ch)*DI*DSTATE + t*NS;
  float4* Pp = (float4*)(Pb + base);
  float4* Gp = (float4*)(Gb + base);
  Pp[0] = make_float4(P[0],P[1],P[2],P[3]);
  Pp[1] = make_float4(P[4],P[5],P[6],P[7]);
  Gp[0] = make_float4(G[0],G[1],G[2],G[3]);
  Gp[1] = make_float4(G[4],G[5],G[6],G[7]);
}

// ---------------- Kernel 5: scan pass 2 — parallel (Hillis-Steele) prefix over chunks ----
__global__ void k_scan2(const float* __restrict__ Pb, const float* __restrict__ Gb,
                        float* __restrict__ Hin){
  int k = blockIdx.x / DI;
  int d = blockIdx.x % DI;
  int c = threadIdx.x;   // chunk id, 256 threads
  float P[DSTATE], G[DSTATE];
  const float* Pp = Pb + ((size_t)(k*NCHUNK + c)*DI + d)*DSTATE;
  const float* Gp = Gb + ((size_t)(k*NCHUNK + c)*DI + d)*DSTATE;
  #pragma unroll
  for (int n = 0; n < DSTATE; n++){ P[n] = Pp[n]; G[n] = Gp[n]; }
  __shared__ float sP[NCHUNK][DSTATE + 1];
  __shared__ float sG[NCHUNK][DSTATE + 1];
  for (int off = 1; off < NCHUNK; off <<= 1){
    #pragma unroll
    for (int n = 0; n < DSTATE; n++){ sP[c][n] = P[n]; sG[c][n] = G[n]; }
    __syncthreads();
    if (c >= off){
      #pragma unroll
      for (int n = 0; n < DSTATE; n++){
        float a1 = sP[c - off][n], b1 = sG[c - off][n];
        G[n] = P[n]*b1 + G[n];
        P[n] = P[n]*a1;
      }
    }
    __syncthreads();
  }
  #pragma unroll
  for (int n = 0; n < DSTATE; n++) sG[c][n] = G[n];
  __syncthreads();
  float* Hp = Hin + ((size_t)(k*NCHUNK + c)*DI + d)*DSTATE;
  #pragma unroll
  for (int n = 0; n < DSTATE; n++) Hp[n] = (c == 0) ? 0.f : sG[c - 1][n];
}

// ---------------- Kernel 6: scan pass 3 — replay chunks, emit out_y ----------------
__global__ __launch_bounds__(384) void k_scan3(
    const float* __restrict__ xdbl, const float* __restrict__ xc,
    const float* __restrict__ dtw, const float* __restrict__ dtb,
    const float* __restrict__ alogs, const float* __restrict__ Dsv,
    const float* __restrict__ Hin, float* __restrict__ outy){
  int k  = blockIdx.x >> 8;
  int ch = blockIdx.x & 255;
  int l0 = ch * CHUNK;
  int t  = threadIdx.x;
  int d  = t >> 1, half = t & 1;
  __shared__ float sdt[CHUNK][8];
  __shared__ float sB[CHUNK][16];
  __shared__ float sC[CHUNK][16];
  __shared__ float sxc[CHUNK][DI];
  for (int j = t; j < CHUNK*NC; j += 384){
    int i = j / NC, c = j % NC;
    float v = xdbl[(size_t)(k*L + l0)*NC + j];
    if (c < DTR) sdt[i][c] = v;
    else if (c < DTR + DSTATE) sB[i][c - DTR] = v;
    else sC[i][c - DTR - DSTATE] = v;
  }
  for (int j = t; j < CHUNK*DI; j += 384){
    int i = j / DI, dd = j % DI;
    sxc[i][dd] = xc[spat(k, l0 + i)*DI + dd];
  }
  float wr[DTR];
  #pragma unroll
  for (int r = 0; r < DTR; r++) wr[r] = dtw[(k*DI + d)*DTR + r];
  float bb = dtb[k*DI + d];
  float A2[NS];
  const float* ap = alogs + (k*DI + d)*DSTATE + half*NS;
  #pragma unroll
  for (int j = 0; j < NS; j++) A2[j] = -__expf(ap[j]) * LOG2E;
  float h[NS];
  size_t hbase = (size_t)(k*NCHUNK + ch)*DI*DSTATE + t*NS;
  float4 h0 = ((const float4*)(Hin + hbase))[0];
  float4 h1 = ((const float4*)(Hin + hbase))[1];
  h[0]=h0.x; h[1]=h0.y; h[2]=h0.z; h[3]=h0.w;
  h[4]=h1.x; h[5]=h1.y; h[6]=h1.z; h[7]=h1.w;
  float Dv = Dsv[k*DI + d];
  __syncthreads();
  #pragma unroll
  for (int i = 0; i < CHUNK; i++){
    float xval = sxc[i][d];
    float dv = bb;
    #pragma unroll
    for (int r = 0; r < DTR; r++) dv += wr[r] * sdt[i][r];
    dv = softplus_f(dv);
    float tv = dv * xval;
    float4 b0 = *(const float4*)&sB[i][half*8];
    float4 b1 = *(const float4*)&sB[i][half*8 + 4];
    float4 c0 = *(const float4*)&sC[i][half*8];
    float4 c1 = *(const float4*)&sC[i][half*8 + 4];
    float Bv[NS] = {b0.x,b0.y,b0.z,b0.w,b1.x,b1.y,b1.z,b1.w};
    float Cv[NS] = {c0.x,c0.y,c0.z,c0.w,c1.x,c1.y,c1.z,c1.w};
    float y = (half == 0) ? Dv * xval : 0.f;
    #pragma unroll
    for (int j = 0; j < NS; j++){
      float dA = exp2f(dv * A2[j]);
      h[j] = dA * h[j] + tv * Bv[j];
      y += h[j] * Cv[j];
    }
    y += __shfl_xor(y, 1);
    if (half == 0) outy[(size_t)(k*L + l0 + i)*DI + d] = y;
  }
}

// ---------------- Kernel 7: sum over k + LayerNorm + *silu(z) + out proj ----------------
__global__ void k_final(const float* __restrict__ outy, const float* __restrict__ sz,
                        const float* __restrict__ g, const float* __restrict__ b,
                        const float* __restrict__ owT, float* __restrict__ out){
  int l = blockIdx.x, t = threadIdx.x;  // 192 threads
  __shared__ float ym[DI];
  __shared__ float part[DI];
  __shared__ float red[6];
  float y = 0.f;
  #pragma unroll
  for (int k = 0; k < KD; k++) y += outy[(size_t)(k*L + l)*DI + t];
  float s = y, s2 = y*y;
  #pragma unroll
  for (int off = 32; off; off >>= 1){ s += __shfl_down(s, off); s2 += __shfl_down(s2, off); }
  int wave = t >> 6, lane = t & 63;
  if (lane == 0){ red[wave] = s; red[3 + wave] = s2; }
  __syncthreads();
  float S  = red[0] + red[1] + red[2];
  float SQ = red[3] + red[4] + red[5];
  float mu  = S * (1.f/DI);
  float var = SQ * (1.f/DI) - mu*mu;
  float yn = (y - mu) * rsqrtf(var + 1e-5f) * g[t] + b[t];
  ym[t] = yn * sz[(size_t)l*DI + t];
  __syncthreads();
  int o  = (t < DM) ? t : (t - DM);
  int d0 = (t < DM) ? 0 : DM;
  float acc = 0.f;
  #pragma unroll 8
  for (int dd = 0; dd < DM; dd++){
    int d = d0 + dd;
    acc += ym[d] * owT[d*DM + o];
  }
  part[t] = acc;
  __syncthreads();
  if (t < DM) out[l*DM + t] = part[t] + part[DM + t];
}

extern "C" void kernel_launch(void* const* d_in, const int* in_sizes, int n_in,
                              void* d_out, int out_size, void* d_ws, size_t ws_size,
                              hipStream_t stream){
  const float* x   = (const float*)d_in[0];
  const float* ipw = (const float*)d_in[1];
  const float* cw  = (const float*)d_in[2];
  const float* cb  = (const float*)d_in[3];
  const float* pw  = (const float*)d_in[4];
  const float* dtw = (const float*)d_in[5];
  const float* dtb = (const float*)d_in[6];
  const float* alg = (const float*)d_in[7];
  const float* Dsv = (const float*)d_in[8];
  const float* lng = (const float*)d_in[9];
  const float* lnb = (const float*)d_in[10];
  const float* ow  = (const float*)d_in[11];
  float* out = (float*)d_out;

  float* ws    = (float*)d_ws;
  float* x_    = ws; ws += L*DI;
  float* sz    = ws; ws += L*DI;
  float* xc    = ws; ws += L*DI;
  float* xdbl  = ws; ws += KD*L*NC;
  float* Pb    = ws; ws += KD*NCHUNK*DI*DSTATE;
  float* Gb    = ws; ws += KD*NCHUNK*DI*DSTATE;
  float* Hin   = ws; ws += KD*NCHUNK*DI*DSTATE;
  float* oy    = ws; ws += KD*L*DI;
  float* ipwT  = ws; ws += 384*DM;
  float* pwT   = ws; ws += KD*NC*DI;
  float* owT   = ws; ws += DM*DI;

  k_prep<<<(384*DM + KD*NC*DI + DM*DI + 255)/256, 256, 0, stream>>>(ipw, pw, ow, ipwT, pwT, owT);
  k_inproj<<<L/TL, 384, 0, stream>>>(x, ipwT, x_, sz);
  k_conv<<<(L*DI + 255)/256, 256, 0, stream>>>(x_, cw, cb, xc);
  k_xdbl<<<KD*512, 320, 0, stream>>>(xc, pwT, xdbl);
  k_scan1<<<KD*NCHUNK, 384, 0, stream>>>(xdbl, xc, dtw, dtb, alg, Pb, Gb);
  k_scan2<<<KD*DI, NCHUNK, 0, stream>>>(Pb, Gb, Hin);
  k_scan3<<<KD*NCHUNK, 384, 0, stream>>>(xdbl, xc, dtw, dtb, alg, Dsv, Hin, oy);
  k_final<<<L, DI, 0, stream>>>(oy, sz, lng, lnb, owT, out);
}